// Round 7
// baseline (125.809 us; speedup 1.0000x reference)
//
#include <hip/hip_runtime.h>

// FeaturePropagationV2: 3-NN inverse-distance interpolation + Linear, fused as:
//   G = feature2 @ W.T          (precomputed once, 8192x256)
//   out[i] = sum_k w_k * G[idx_k] + b
//
// kNN, point-per-lane orientation, two-pass half-slab (spill-proof):
//   Each wave owns a 1024-pt slab, processed as 2 halves of 8 slots
//   (32 named VGPRs resident at a time; halves loop unroll-1 so the
//   compiler cannot overlap the halves' live ranges).
//   Phase 1 (lane=query): slab's first 256 pts staged in LDS, uniform
//            broadcast reads, sloppy batch-min top-4 -> per-query threshold.
//   Phase 2 (lane=point): per query, broadcast q via readlane; per slot
//            3 FMA + cmp covers 64 pairs; survivors via __ballot walk.
//            Survivor count persists across halves in LDS.
//   Select : exact reference-f32 re-score, stable (d2,idx) top-3 (validated).

#define FLT_BIG 3.402823466e+38f
#define CAP     16
#define MARGIN  3e-5f

__device__ __forceinline__ float rlf(float v, int l) {
    return __uint_as_float((unsigned)__builtin_amdgcn_readlane((int)__float_as_uint(v), l));
}

__global__ __launch_bounds__(256) void prep_kernel(const float* __restrict__ xyz2,
                                                   float4* __restrict__ pack, int N2) {
    int j = blockIdx.x * 256 + threadIdx.x;
    if (j < N2) {
        float x = xyz2[3 * j + 0];
        float y = xyz2[3 * j + 1];
        float z = xyz2[3 * j + 2];
        float4 p;
        p.x = x; p.y = y; p.z = z;
        p.w = 0.5f * (x * x + y * y + z * z);   // scan metric only
        pack[j] = p;
    }
}

// C[m][n] = sum_k A[m][k] * B[n][k]   (unchanged)
__global__ __launch_bounds__(256) void gemm_nt_f32(const float* __restrict__ A,
                                                   const float* __restrict__ B,
                                                   float* __restrict__ C,
                                                   int M, int N, int K) {
    __shared__ float As[64][68];
    __shared__ float Bs[64][68];

    const int t  = threadIdx.x;
    const int tx = t & 15;
    const int ty = t >> 4;
    const int bm = blockIdx.x * 64;
    const int bn = blockIdx.y * 64;

    float acc[4][4] = {{0.f}};

    for (int kt = 0; kt < K; kt += 64) {
#pragma unroll
        for (int rr = 0; rr < 4; ++rr) {
            int r = ty + 16 * rr;
            int c = tx * 4;
            float4 av = *(const float4*)(A + (size_t)(bm + r) * K + kt + c);
            As[c + 0][r] = av.x;
            As[c + 1][r] = av.y;
            As[c + 2][r] = av.z;
            As[c + 3][r] = av.w;
            float4 bv = *(const float4*)(B + (size_t)(bn + r) * K + kt + c);
            Bs[c + 0][r] = bv.x;
            Bs[c + 1][r] = bv.y;
            Bs[c + 2][r] = bv.z;
            Bs[c + 3][r] = bv.w;
        }
        __syncthreads();

#pragma unroll 8
        for (int k = 0; k < 64; ++k) {
            float4 a4 = *(const float4*)&As[k][ty * 4];
            float4 b4 = *(const float4*)&Bs[k][tx * 4];
            float a[4] = {a4.x, a4.y, a4.z, a4.w};
            float b[4] = {b4.x, b4.y, b4.z, b4.w};
#pragma unroll
            for (int i = 0; i < 4; ++i)
#pragma unroll
                for (int j = 0; j < 4; ++j)
                    acc[i][j] = fmaf(a[i], b[j], acc[i][j]);
        }
        __syncthreads();
    }

#pragma unroll
    for (int i = 0; i < 4; ++i) {
        float4 v;
        v.x = acc[i][0]; v.y = acc[i][1]; v.z = acc[i][2]; v.w = acc[i][3];
        *(float4*)(C + (size_t)(bm + ty * 4 + i) * N + bn + tx * 4) = v;
    }
}

// branchless value-only sorted top-4 insert: 7 min/max ops
#define TOP4V_INSERT(mv)                                           \
    do {                                                           \
        float _x  = (mv);                                          \
        float _n0 = fminf(b0, _x);  float _y0 = fmaxf(b0, _x); b0 = _n0; \
        float _n1 = fminf(b1, _y0); float _y1 = fmaxf(b1, _y0); b1 = _n1; \
        float _n2 = fminf(b2, _y1); float _y2 = fmaxf(b2, _y1); b2 = _n2; \
        b3 = fminf(b3, _y2);                                       \
    } while (0)

// stable (dd, j) insert into sorted top-3 (d0<=d1<=d2v), idx tiebreak
#define TOP3JD_INSERT(dd, j)                                       \
    do {                                                           \
        bool lt2 = ((dd) < d2v) || ((dd) == d2v && (j) < j2);      \
        if (lt2) {                                                 \
            bool lt1 = ((dd) < d1) || ((dd) == d1 && (j) < j1);    \
            if (lt1) {                                             \
                d2v = d1; j2 = j1;                                 \
                bool lt0 = ((dd) < d0) || ((dd) == d0 && (j) < j0);\
                if (lt0) { d1 = d0; j1 = j0; d0 = (dd); j0 = (j); }\
                else     { d1 = (dd); j1 = (j); }                  \
            } else { d2v = (dd); j2 = (j); }                       \
        }                                                          \
    } while (0)

// named half-slab registers — literal indices only (spill-proof)
#define DECLS(s) float px##s, py##s, pz##s, pw##s;
#define LOADH(s) { float4 _p = pack[jb + ((s) << 6) + lane]; \
                   px##s = _p.x; py##s = _p.y; pz##s = _p.z; pw##s = _p.w; }
// phase-2 slot: 3 FMA (threshold as seed) + 1 cmp covers 64 pairs
#define SLOTF(s)                                                               \
    {                                                                          \
        float acc = fmaf(qxx, px##s, fmaf(qyy, py##s, fmaf(qzz, pz##s, tq))); \
        unsigned long long mk = __ballot(acc >= pw##s);                        \
        while (mk) {                                                           \
            int l = __builtin_ctzll(mk);                                       \
            mk &= mk - 1;                                                      \
            if (lane == 0 && cnt < CAP)                                        \
                ring[q][wave][cnt] = (unsigned short)(jb + ((s) << 6) + l);    \
            ++cnt;                                                             \
        }                                                                      \
    }
#define X8(M) M(0) M(1) M(2) M(3) M(4) M(5) M(6) M(7)

// Block: 512 threads = 8 waves, owns 64 fine points (queries).
// Wave w owns coarse slab [w*1024,(w+1)*1024).
__global__ __launch_bounds__(512, 4) void knn_gather(const float* __restrict__ xyz1,
                                                     const float4* __restrict__ pack,
                                                     const float4* __restrict__ G4,    // [N2*64]
                                                     const float4* __restrict__ bias4, // [64]
                                                     float4* __restrict__ out4,        // [N1*64]
                                                     int N2) {
    __shared__ float4         samp[8][256];     // 32 KB: phase-1 sample stage
    __shared__ float          md[8][64][4];
    __shared__ int            mi[8][64][3];
    __shared__ float          thr[64];
    __shared__ unsigned short ring[64][8][CAP]; // [q][w][e]: w-stride 32 B -> 2-way
    __shared__ unsigned short cnts[64][8];
    __shared__ float          swgt[64][3];
    __shared__ int            sidx[64][3];

    const int tid  = threadIdx.x;
    const int wave = __builtin_amdgcn_readfirstlane(tid >> 6);
    const int lane = tid & 63;
    const int fine = blockIdx.x * 64 + lane;

    const float qx = xyz1[3 * fine + 0];
    const float qy = xyz1[3 * fine + 1];
    const float qz = xyz1[3 * fine + 2];

    const int chunk = N2 >> 3;                 // 1024
    const int base  = wave * chunk;            // wave-uniform (SGPR)

    // ---- stage phase-1 sample (slab's first 256 pts) in LDS ----
#pragma unroll
    for (int k = 0; k < 4; ++k)
        samp[wave][(k << 6) + lane] = pack[base + (k << 6) + lane];
    __syncthreads();

    // ---- Phase 1 (lane = query): batch-min(4) sloppy top-4 over 256 sample
    {
        float b0 = FLT_BIG, b1 = FLT_BIG, b2 = FLT_BIG, b3 = FLT_BIG;
        const float4* sp = samp[wave];
#pragma unroll 1
        for (int k = 0; k < 256; k += 4) {
            float4 p0 = sp[k + 0];              // uniform addr -> broadcast
            float4 p1 = sp[k + 1];
            float4 p2 = sp[k + 2];
            float4 p3 = sp[k + 3];
            float m0 = p0.w - fmaf(qx, p0.x, fmaf(qy, p0.y, qz * p0.z));
            float m1 = p1.w - fmaf(qx, p1.x, fmaf(qy, p1.y, qz * p1.z));
            float m2 = p2.w - fmaf(qx, p2.x, fmaf(qy, p2.y, qz * p2.z));
            float m3 = p3.w - fmaf(qx, p3.x, fmaf(qy, p3.y, qz * p3.z));
            float mm = fminf(fminf(m0, m1), fminf(m2, m3));  // batch-min:
            TOP4V_INSERT(mm);                   // under-maintains -> larger t (safe)
        }
        md[wave][lane][0] = b0;
        md[wave][lane][1] = b1;
        md[wave][lane][2] = b2;
        md[wave][lane][3] = b3;
    }
    __syncthreads();

    if (tid < 64) {
        float b0 = FLT_BIG, b1 = FLT_BIG, b2 = FLT_BIG, b3 = FLT_BIG;
#pragma unroll
        for (int w = 0; w < 8; ++w)
#pragma unroll
            for (int k = 0; k < 4; ++k)
                TOP4V_INSERT(md[w][tid][k]);
        thr[tid] = b3 + MARGIN;   // sample-4th >= true-3rd; margin covers
    }                              // formula-rounding differences vs ref d2
    __syncthreads();

    // ---- Phase 2 (lane = point), two half-slab passes of 8 slots each ----
    {
        const float qt_own = thr[lane];
#pragma unroll 1
        for (int h = 0; h < 2; ++h) {
            const int jb = base + (h << 9);    // half base (SGPR)
            X8(DECLS)
            X8(LOADH)
#pragma unroll 1
            for (int q = 0; q < 64; ++q) {
                float qxx = rlf(qx, q);
                float qyy = rlf(qy, q);
                float qzz = rlf(qz, q);
                float tq  = rlf(qt_own, q);
                int cnt = h ? (int)cnts[q][wave] : 0;   // persist across halves
                X8(SLOTF)
                cnts[q][wave] = (unsigned short)cnt;    // raw; clamped at read
            }
        }
    }
    __syncthreads();

    // ---- Selection stage A: thread (q,w) scores ring[q][w] with the exact
    //      reference-f32 formula, keeps stable top-3 ----
    {
        const int q  = tid >> 3;
        const int w  = tid & 7;
        const int fq = blockIdx.x * 64 + q;
        const float sqx = xyz1[3 * fq + 0];
        const float sqy = xyz1[3 * fq + 1];
        const float sqz = xyz1[3 * fq + 2];
        // q_sq = (qx*qx + qy*qy) + qz*qz  (no contraction, ref rounding)
        const float qsq = __fadd_rn(__fadd_rn(__fmul_rn(sqx, sqx), __fmul_rn(sqy, sqy)),
                                    __fmul_rn(sqz, sqz));
        float d0 = FLT_BIG, d1 = FLT_BIG, d2v = FLT_BIG;
        int   j0 = 0x7fffffff, j1 = 0x7fffffff, j2 = 0x7fffffff;
        const int n = min((int)cnts[q][w], CAP);
        for (int e = 0; e < n; ++e) {
            const int j = ring[q][w][e];
            float4 p = pack[j];
            // x2_sq = (x*x + y*y) + z*z
            float x2s = __fadd_rn(__fadd_rn(__fmul_rn(p.x, p.x), __fmul_rn(p.y, p.y)),
                                  __fmul_rn(p.z, p.z));
            // dot = fma(qz,z, fma(qy,y, rn(qx*x)))  — BLAS k-ascending chain
            float dot = __fmaf_rn(sqz, p.z, __fmaf_rn(sqy, p.y, __fmul_rn(sqx, p.x)));
            // d2 = (q_sq + x2_sq) - 2*dot
            float dd = __fsub_rn(__fadd_rn(qsq, x2s), __fmul_rn(2.0f, dot));
            TOP3JD_INSERT(dd, j);
        }
        md[w][q][0] = d0;  md[w][q][1] = d1;  md[w][q][2] = d2v;
        mi[w][q][0] = j0;  mi[w][q][1] = j1;  mi[w][q][2] = j2;
    }
    __syncthreads();

    // ---- Selection stage B: one thread per query merges 8x3, weights ----
    if (tid < 64) {
        float d0 = FLT_BIG, d1 = FLT_BIG, d2v = FLT_BIG;
        int   j0 = 0x7fffffff, j1 = 0x7fffffff, j2 = 0x7fffffff;
#pragma unroll
        for (int w = 0; w < 8; ++w)
#pragma unroll
            for (int k = 0; k < 3; ++k) {
                float dd = md[w][tid][k];
                int   j  = mi[w][tid][k];
                TOP3JD_INSERT(dd, j);
            }
        // f32 inverse-distance weights, reference op order
        float w0 = 1.0f / (__fadd_rn(sqrtf(fmaxf(d0,  1e-12f)), 1e-8f));
        float w1 = 1.0f / (__fadd_rn(sqrtf(fmaxf(d1,  1e-12f)), 1e-8f));
        float w2 = 1.0f / (__fadd_rn(sqrtf(fmaxf(d2v, 1e-12f)), 1e-8f));
        float wsum = __fadd_rn(__fadd_rn(w0, w1), w2);
        swgt[tid][0] = w0 / wsum; sidx[tid][0] = j0;
        swgt[tid][1] = w1 / wsum; sidx[tid][1] = j1;
        swgt[tid][2] = w2 / wsum; sidx[tid][2] = j2;
    }
    __syncthreads();

    // ---- Gather: out[fine] = w0*G[j0] + w1*G[j1] + w2*G[j2] + b ----
    const float4 bb = bias4[lane];
#pragma unroll
    for (int p = 0; p < 8; ++p) {
        int fl = wave * 8 + p;
        float w0 = swgt[fl][0];
        float w1 = swgt[fl][1];
        float w2 = swgt[fl][2];
        int j0 = sidx[fl][0];
        int j1 = sidx[fl][1];
        int j2 = sidx[fl][2];
        float4 g0 = G4[(size_t)j0 * 64 + lane];
        float4 g1 = G4[(size_t)j1 * 64 + lane];
        float4 g2 = G4[(size_t)j2 * 64 + lane];
        float4 o;
        o.x = fmaf(w0, g0.x, fmaf(w1, g1.x, fmaf(w2, g2.x, bb.x)));
        o.y = fmaf(w0, g0.y, fmaf(w1, g1.y, fmaf(w2, g2.y, bb.y)));
        o.z = fmaf(w0, g0.z, fmaf(w1, g1.z, fmaf(w2, g2.z, bb.z)));
        o.w = fmaf(w0, g0.w, fmaf(w1, g1.w, fmaf(w2, g2.w, bb.w)));
        out4[(size_t)(blockIdx.x * 64 + fl) * 64 + lane] = o;
    }
}

extern "C" void kernel_launch(void* const* d_in, const int* in_sizes, int n_in,
                              void* d_out, int out_size, void* d_ws, size_t ws_size,
                              hipStream_t stream) {
    const float* xyz1 = (const float*)d_in[0];
    const float* xyz2 = (const float*)d_in[1];
    // d_in[2] = feature1 (unused by the reference computation)
    const float* f2   = (const float*)d_in[3];
    const float* W    = (const float*)d_in[6];
    const float* bias = (const float*)d_in[7];

    const int N1  = in_sizes[0] / 3;   // 32768
    const int N2  = in_sizes[1] / 3;   // 8192
    const int C   = in_sizes[3] / N2;  // 256
    const int OUT = in_sizes[7];       // 256

    float*  G    = (float*)d_ws;                                   // N2*OUT f32 = 8 MB
    float4* pack = (float4*)((char*)d_ws + (size_t)N2 * OUT * 4);  // N2 float4 = 128 KB

    prep_kernel<<<(N2 + 255) / 256, 256, 0, stream>>>(xyz2, pack, N2);

    dim3 ggrid(N2 / 64, OUT / 64);
    gemm_nt_f32<<<ggrid, 256, 0, stream>>>(f2, W, G, N2, OUT, C);

    knn_gather<<<N1 / 64, 512, 0, stream>>>(xyz1, pack, (const float4*)G,
                                            (const float4*)bias, (float4*)d_out, N2);
}

// Round 8
// 117.704 us; speedup vs baseline: 1.0689x; 1.0689x over previous
//
#include <hip/hip_runtime.h>

// FeaturePropagationV2: 3-NN inverse-distance interpolation + Linear, fused as:
//   G = feature2 @ W.T          (precomputed once, 8192x256)
//   out[i] = sum_k w_k * G[idx_k] + b
//
// kNN, point-per-lane, single-pass 16-slot slab (VGPR budget via
// __launch_bounds__(512,4) -> 128 regs, demand ~84, no spill):
//   Phase 1 (lane=query): slab's first 256 pts staged in LDS from the slab
//            regs, uniform broadcast reads, sloppy batch-min top-4 -> thr.
//   Phase 2 (lane=point): per query, broadcast q via readlane; per slot
//            3 FMA + cmp covers 64 pairs; survivors via uniform ballot-walk
//            (cnt in scalar flow, lane-0 ring write).
//   Select : exact reference-f32 re-score, stable (d2,idx) top-3 (validated).
// LDS layouts chosen so row strides are not multiples of 128 B (bank-safe).

#define FLT_BIG 3.402823466e+38f
#define CAP     16
#define MARGIN  3e-5f

__device__ __forceinline__ float rlf(float v, int l) {
    return __uint_as_float((unsigned)__builtin_amdgcn_readlane((int)__float_as_uint(v), l));
}

__global__ __launch_bounds__(256) void prep_kernel(const float* __restrict__ xyz2,
                                                   float4* __restrict__ pack, int N2) {
    int j = blockIdx.x * 256 + threadIdx.x;
    if (j < N2) {
        float x = xyz2[3 * j + 0];
        float y = xyz2[3 * j + 1];
        float z = xyz2[3 * j + 2];
        float4 p;
        p.x = x; p.y = y; p.z = z;
        p.w = 0.5f * (x * x + y * y + z * z);   // scan metric only
        pack[j] = p;
    }
}

// C[m][n] = sum_k A[m][k] * B[n][k]   (unchanged)
__global__ __launch_bounds__(256) void gemm_nt_f32(const float* __restrict__ A,
                                                   const float* __restrict__ B,
                                                   float* __restrict__ C,
                                                   int M, int N, int K) {
    __shared__ float As[64][68];
    __shared__ float Bs[64][68];

    const int t  = threadIdx.x;
    const int tx = t & 15;
    const int ty = t >> 4;
    const int bm = blockIdx.x * 64;
    const int bn = blockIdx.y * 64;

    float acc[4][4] = {{0.f}};

    for (int kt = 0; kt < K; kt += 64) {
#pragma unroll
        for (int rr = 0; rr < 4; ++rr) {
            int r = ty + 16 * rr;
            int c = tx * 4;
            float4 av = *(const float4*)(A + (size_t)(bm + r) * K + kt + c);
            As[c + 0][r] = av.x;
            As[c + 1][r] = av.y;
            As[c + 2][r] = av.z;
            As[c + 3][r] = av.w;
            float4 bv = *(const float4*)(B + (size_t)(bn + r) * K + kt + c);
            Bs[c + 0][r] = bv.x;
            Bs[c + 1][r] = bv.y;
            Bs[c + 2][r] = bv.z;
            Bs[c + 3][r] = bv.w;
        }
        __syncthreads();

#pragma unroll 8
        for (int k = 0; k < 64; ++k) {
            float4 a4 = *(const float4*)&As[k][ty * 4];
            float4 b4 = *(const float4*)&Bs[k][tx * 4];
            float a[4] = {a4.x, a4.y, a4.z, a4.w};
            float b[4] = {b4.x, b4.y, b4.z, b4.w};
#pragma unroll
            for (int i = 0; i < 4; ++i)
#pragma unroll
                for (int j = 0; j < 4; ++j)
                    acc[i][j] = fmaf(a[i], b[j], acc[i][j]);
        }
        __syncthreads();
    }

#pragma unroll
    for (int i = 0; i < 4; ++i) {
        float4 v;
        v.x = acc[i][0]; v.y = acc[i][1]; v.z = acc[i][2]; v.w = acc[i][3];
        *(float4*)(C + (size_t)(bm + ty * 4 + i) * N + bn + tx * 4) = v;
    }
}

// branchless value-only sorted top-4 insert: 7 min/max ops
#define TOP4V_INSERT(mv)                                           \
    do {                                                           \
        float _x  = (mv);                                          \
        float _n0 = fminf(b0, _x);  float _y0 = fmaxf(b0, _x); b0 = _n0; \
        float _n1 = fminf(b1, _y0); float _y1 = fmaxf(b1, _y0); b1 = _n1; \
        float _n2 = fminf(b2, _y1); float _y2 = fmaxf(b2, _y1); b2 = _n2; \
        b3 = fminf(b3, _y2);                                       \
    } while (0)

// stable (dd, j) insert into sorted top-3 (d0<=d1<=d2v), idx tiebreak
#define TOP3JD_INSERT(dd, j)                                       \
    do {                                                           \
        bool lt2 = ((dd) < d2v) || ((dd) == d2v && (j) < j2);      \
        if (lt2) {                                                 \
            bool lt1 = ((dd) < d1) || ((dd) == d1 && (j) < j1);    \
            if (lt1) {                                             \
                d2v = d1; j2 = j1;                                 \
                bool lt0 = ((dd) < d0) || ((dd) == d0 && (j) < j0);\
                if (lt0) { d1 = d0; j1 = j0; d0 = (dd); j0 = (j); }\
                else     { d1 = (dd); j1 = (j); }                  \
            } else { d2v = (dd); j2 = (j); }                       \
        }                                                          \
    } while (0)

// named slab registers — literal indices only (spill-proof with 128-reg budget)
#define DECLS(s) float px##s, py##s, pz##s, pw##s;
#define LOADS(s) { float4 _p = pack[base + ((s) << 6) + lane]; \
                   px##s = _p.x; py##s = _p.y; pz##s = _p.z; pw##s = _p.w; }
#define SAMPW(s) samp[wave][((s) << 6) + lane] = make_float4(px##s, py##s, pz##s, pw##s);
// phase-2 slot: 3 FMA (threshold as seed) + 1 cmp covers 64 pairs;
// survivor walk is uniform-scalar, lane 0 writes the ring
#define SLOTF(s)                                                               \
    {                                                                          \
        float acc = fmaf(qxx, px##s, fmaf(qyy, py##s, fmaf(qzz, pz##s, tq))); \
        unsigned long long mk = __ballot(acc >= pw##s);                        \
        while (mk) {                                                           \
            int l = __builtin_ctzll(mk);                                       \
            mk &= mk - 1;                                                      \
            if (is0 && cnt < CAP)                                              \
                myring[cnt] = (unsigned short)(base + ((s) << 6) + l);         \
            ++cnt;                                                             \
        }                                                                      \
    }
#define X16(M) M(0) M(1) M(2) M(3) M(4) M(5) M(6) M(7) \
               M(8) M(9) M(10) M(11) M(12) M(13) M(14) M(15)
#define X4(M)  M(0) M(1) M(2) M(3)

// Block: 512 threads = 8 waves, owns 64 fine points (queries).
// Wave w owns coarse slab [w*1024,(w+1)*1024), 16 pts/lane in named regs.
__global__ __launch_bounds__(512, 4) void knn_gather(const float* __restrict__ xyz1,
                                                     const float4* __restrict__ pack,
                                                     const float4* __restrict__ G4,    // [N2*64]
                                                     const float4* __restrict__ bias4, // [64]
                                                     float4* __restrict__ out4,        // [N1*64]
                                                     int N2) {
    __shared__ float4         samp[8][256];      // 32 KB: phase-1 sample stage
    __shared__ float          mdl[64][25];       // [q][w*3+k] row 100 B (+ph1 reuse [q][w*4+k])
    __shared__ float          mdl4[64][33];      // phase-1 top4 stage [q][w*4+k] row 132 B
    __shared__ int            mil[64][25];       // [q][w*3+k]
    __shared__ float          thr[64];
    __shared__ unsigned short ring[64][8 * CAP + 1];  // [q][w*CAP+e] row 258 B
    __shared__ unsigned short cnts[64][8];
    __shared__ float          swgt[64][3];
    __shared__ int            sidx[64][3];

    const int tid  = threadIdx.x;
    const int wave = __builtin_amdgcn_readfirstlane(tid >> 6);
    const int lane = tid & 63;
    const int fine = blockIdx.x * 64 + lane;

    const float qx = xyz1[3 * fine + 0];
    const float qy = xyz1[3 * fine + 1];
    const float qz = xyz1[3 * fine + 2];

    const int chunk = N2 >> 3;                 // 1024
    const int base  = wave * chunk;            // wave-uniform (SGPR)

    // ---- preload slab: 16 named float4 per lane; stage sample from regs ----
    X16(DECLS)
    X16(LOADS)
    X4(SAMPW)
    __syncthreads();

    // ---- Phase 1 (lane = query): batch-min(4) sloppy top-4 over 256 sample
    {
        float b0 = FLT_BIG, b1 = FLT_BIG, b2 = FLT_BIG, b3 = FLT_BIG;
        const float4* sp = samp[wave];
#pragma unroll 2
        for (int k = 0; k < 256; k += 4) {
            float4 p0 = sp[k + 0];              // uniform addr -> broadcast
            float4 p1 = sp[k + 1];
            float4 p2 = sp[k + 2];
            float4 p3 = sp[k + 3];
            float m0 = p0.w - fmaf(qx, p0.x, fmaf(qy, p0.y, qz * p0.z));
            float m1 = p1.w - fmaf(qx, p1.x, fmaf(qy, p1.y, qz * p1.z));
            float m2 = p2.w - fmaf(qx, p2.x, fmaf(qy, p2.y, qz * p2.z));
            float m3 = p3.w - fmaf(qx, p3.x, fmaf(qy, p3.y, qz * p3.z));
            float mm = fminf(fminf(m0, m1), fminf(m2, m3));  // batch-min:
            TOP4V_INSERT(mm);                   // under-maintains -> larger t (safe)
        }
        mdl4[lane][wave * 4 + 0] = b0;
        mdl4[lane][wave * 4 + 1] = b1;
        mdl4[lane][wave * 4 + 2] = b2;
        mdl4[lane][wave * 4 + 3] = b3;
    }
    __syncthreads();

    if (tid < 64) {
        float b0 = FLT_BIG, b1 = FLT_BIG, b2 = FLT_BIG, b3 = FLT_BIG;
#pragma unroll
        for (int w = 0; w < 8; ++w)
#pragma unroll
            for (int k = 0; k < 4; ++k)
                TOP4V_INSERT(mdl4[tid][w * 4 + k]);
        thr[tid] = b3 + MARGIN;   // sample-4th >= true-3rd; margin covers
    }                              // formula-rounding differences vs ref d2
    __syncthreads();

    // ---- Phase 2 (lane = point): per query broadcast, ballot-filter ----
    {
        const float qt_own = thr[lane];
        const bool  is0    = (lane == 0);
#pragma unroll 1
        for (int q = 0; q < 64; ++q) {
            float qxx = rlf(qx, q);
            float qyy = rlf(qy, q);
            float qzz = rlf(qz, q);
            float tq  = rlf(qt_own, q);
            int cnt = 0;
            unsigned short* myring = &ring[q][wave * CAP];
            X16(SLOTF)
            if (is0) cnts[q][wave] = (unsigned short)(cnt < CAP ? cnt : CAP);
        }
    }
    __syncthreads();

    // ---- Selection stage A: thread (q,w) scores ring[q][w] with the exact
    //      reference-f32 formula, keeps stable top-3 ----
    {
        const int q  = tid >> 3;
        const int w  = tid & 7;
        const int fq = blockIdx.x * 64 + q;
        const float sqx = xyz1[3 * fq + 0];
        const float sqy = xyz1[3 * fq + 1];
        const float sqz = xyz1[3 * fq + 2];
        // q_sq = (qx*qx + qy*qy) + qz*qz  (no contraction, ref rounding)
        const float qsq = __fadd_rn(__fadd_rn(__fmul_rn(sqx, sqx), __fmul_rn(sqy, sqy)),
                                    __fmul_rn(sqz, sqz));
        float d0 = FLT_BIG, d1 = FLT_BIG, d2v = FLT_BIG;
        int   j0 = 0x7fffffff, j1 = 0x7fffffff, j2 = 0x7fffffff;
        const int n = (int)cnts[q][w];
        for (int e = 0; e < n; ++e) {
            const int j = ring[q][w * CAP + e];
            float4 p = pack[j];
            // x2_sq = (x*x + y*y) + z*z
            float x2s = __fadd_rn(__fadd_rn(__fmul_rn(p.x, p.x), __fmul_rn(p.y, p.y)),
                                  __fmul_rn(p.z, p.z));
            // dot = fma(qz,z, fma(qy,y, rn(qx*x)))  — BLAS k-ascending chain
            float dot = __fmaf_rn(sqz, p.z, __fmaf_rn(sqy, p.y, __fmul_rn(sqx, p.x)));
            // d2 = (q_sq + x2_sq) - 2*dot
            float dd = __fsub_rn(__fadd_rn(qsq, x2s), __fmul_rn(2.0f, dot));
            TOP3JD_INSERT(dd, j);
        }
        mdl[q][w * 3 + 0] = d0;  mdl[q][w * 3 + 1] = d1;  mdl[q][w * 3 + 2] = d2v;
        mil[q][w * 3 + 0] = j0;  mil[q][w * 3 + 1] = j1;  mil[q][w * 3 + 2] = j2;
    }
    __syncthreads();

    // ---- Selection stage B: one thread per query merges 8x3, weights ----
    if (tid < 64) {
        float d0 = FLT_BIG, d1 = FLT_BIG, d2v = FLT_BIG;
        int   j0 = 0x7fffffff, j1 = 0x7fffffff, j2 = 0x7fffffff;
#pragma unroll
        for (int w = 0; w < 8; ++w)
#pragma unroll
            for (int k = 0; k < 3; ++k) {
                float dd = mdl[tid][w * 3 + k];
                int   j  = mil[tid][w * 3 + k];
                TOP3JD_INSERT(dd, j);
            }
        // f32 inverse-distance weights, reference op order
        float w0 = 1.0f / (__fadd_rn(sqrtf(fmaxf(d0,  1e-12f)), 1e-8f));
        float w1 = 1.0f / (__fadd_rn(sqrtf(fmaxf(d1,  1e-12f)), 1e-8f));
        float w2 = 1.0f / (__fadd_rn(sqrtf(fmaxf(d2v, 1e-12f)), 1e-8f));
        float wsum = __fadd_rn(__fadd_rn(w0, w1), w2);
        swgt[tid][0] = w0 / wsum; sidx[tid][0] = j0;
        swgt[tid][1] = w1 / wsum; sidx[tid][1] = j1;
        swgt[tid][2] = w2 / wsum; sidx[tid][2] = j2;
    }
    __syncthreads();

    // ---- Gather: out[fine] = w0*G[j0] + w1*G[j1] + w2*G[j2] + b ----
    const float4 bb = bias4[lane];
#pragma unroll
    for (int p = 0; p < 8; ++p) {
        int fl = wave * 8 + p;
        float w0 = swgt[fl][0];
        float w1 = swgt[fl][1];
        float w2 = swgt[fl][2];
        int j0 = sidx[fl][0];
        int j1 = sidx[fl][1];
        int j2 = sidx[fl][2];
        float4 g0 = G4[(size_t)j0 * 64 + lane];
        float4 g1 = G4[(size_t)j1 * 64 + lane];
        float4 g2 = G4[(size_t)j2 * 64 + lane];
        float4 o;
        o.x = fmaf(w0, g0.x, fmaf(w1, g1.x, fmaf(w2, g2.x, bb.x)));
        o.y = fmaf(w0, g0.y, fmaf(w1, g1.y, fmaf(w2, g2.y, bb.y)));
        o.z = fmaf(w0, g0.z, fmaf(w1, g1.z, fmaf(w2, g2.z, bb.z)));
        o.w = fmaf(w0, g0.w, fmaf(w1, g1.w, fmaf(w2, g2.w, bb.w)));
        out4[(size_t)(blockIdx.x * 64 + fl) * 64 + lane] = o;
    }
}

extern "C" void kernel_launch(void* const* d_in, const int* in_sizes, int n_in,
                              void* d_out, int out_size, void* d_ws, size_t ws_size,
                              hipStream_t stream) {
    const float* xyz1 = (const float*)d_in[0];
    const float* xyz2 = (const float*)d_in[1];
    // d_in[2] = feature1 (unused by the reference computation)
    const float* f2   = (const float*)d_in[3];
    const float* W    = (const float*)d_in[6];
    const float* bias = (const float*)d_in[7];

    const int N1  = in_sizes[0] / 3;   // 32768
    const int N2  = in_sizes[1] / 3;   // 8192
    const int C   = in_sizes[3] / N2;  // 256
    const int OUT = in_sizes[7];       // 256

    float*  G    = (float*)d_ws;                                   // N2*OUT f32 = 8 MB
    float4* pack = (float4*)((char*)d_ws + (size_t)N2 * OUT * 4);  // N2 float4 = 128 KB

    prep_kernel<<<(N2 + 255) / 256, 256, 0, stream>>>(xyz2, pack, N2);

    dim3 ggrid(N2 / 64, OUT / 64);
    gemm_nt_f32<<<ggrid, 256, 0, stream>>>(f2, W, G, N2, OUT, C);

    knn_gather<<<N1 / 64, 512, 0, stream>>>(xyz1, pack, (const float4*)G,
                                            (const float4*)bias, (float4*)d_out, N2);
}

// Round 9
// 117.606 us; speedup vs baseline: 1.0698x; 1.0008x over previous
//
#include <hip/hip_runtime.h>

// FeaturePropagationV2: 3-NN inverse-distance interpolation + Linear, fused as:
//   G = feature2 @ W.T          (precomputed once, 8192x256)
//   out[i] = sum_k w_k * G[idx_k] + b
//
// kNN, point-per-lane, single-pass 16-slot slab. Register budget pinned via
// amdgpu_waves_per_eu(4,4): min=max=4 waves/EU -> 128-VGPR budget, so the
// 64-reg slab stays resident (launch_bounds' 2nd arg alone is only a MIN —
// the allocator kept targeting 8 waves/EU and rematerialized the slab loads
// inside the hot loop in rounds 5-8).
//   Phase 1 (lane=query): slab's first 256 pts staged in LDS from the slab
//            regs, uniform broadcast reads, sloppy batch-min top-4 -> thr.
//   Phase 2 (lane=point): per query, broadcast q via readlane; per slot
//            3 FMA + cmp covers 64 pairs; survivors via uniform ballot-walk.
//   Select : exact reference-f32 re-score, stable (d2,idx) top-3 (validated).
// LDS row strides avoid multiples of 128 B (bank-safe).

#define FLT_BIG 3.402823466e+38f
#define CAP     16
#define MARGIN  3e-5f

__device__ __forceinline__ float rlf(float v, int l) {
    return __uint_as_float((unsigned)__builtin_amdgcn_readlane((int)__float_as_uint(v), l));
}

__global__ __launch_bounds__(256) void prep_kernel(const float* __restrict__ xyz2,
                                                   float4* __restrict__ pack, int N2) {
    int j = blockIdx.x * 256 + threadIdx.x;
    if (j < N2) {
        float x = xyz2[3 * j + 0];
        float y = xyz2[3 * j + 1];
        float z = xyz2[3 * j + 2];
        float4 p;
        p.x = x; p.y = y; p.z = z;
        p.w = 0.5f * (x * x + y * y + z * z);   // scan metric only
        pack[j] = p;
    }
}

// C[m][n] = sum_k A[m][k] * B[n][k]   (unchanged)
__global__ __launch_bounds__(256) void gemm_nt_f32(const float* __restrict__ A,
                                                   const float* __restrict__ B,
                                                   float* __restrict__ C,
                                                   int M, int N, int K) {
    __shared__ float As[64][68];
    __shared__ float Bs[64][68];

    const int t  = threadIdx.x;
    const int tx = t & 15;
    const int ty = t >> 4;
    const int bm = blockIdx.x * 64;
    const int bn = blockIdx.y * 64;

    float acc[4][4] = {{0.f}};

    for (int kt = 0; kt < K; kt += 64) {
#pragma unroll
        for (int rr = 0; rr < 4; ++rr) {
            int r = ty + 16 * rr;
            int c = tx * 4;
            float4 av = *(const float4*)(A + (size_t)(bm + r) * K + kt + c);
            As[c + 0][r] = av.x;
            As[c + 1][r] = av.y;
            As[c + 2][r] = av.z;
            As[c + 3][r] = av.w;
            float4 bv = *(const float4*)(B + (size_t)(bn + r) * K + kt + c);
            Bs[c + 0][r] = bv.x;
            Bs[c + 1][r] = bv.y;
            Bs[c + 2][r] = bv.z;
            Bs[c + 3][r] = bv.w;
        }
        __syncthreads();

#pragma unroll 8
        for (int k = 0; k < 64; ++k) {
            float4 a4 = *(const float4*)&As[k][ty * 4];
            float4 b4 = *(const float4*)&Bs[k][tx * 4];
            float a[4] = {a4.x, a4.y, a4.z, a4.w};
            float b[4] = {b4.x, b4.y, b4.z, b4.w};
#pragma unroll
            for (int i = 0; i < 4; ++i)
#pragma unroll
                for (int j = 0; j < 4; ++j)
                    acc[i][j] = fmaf(a[i], b[j], acc[i][j]);
        }
        __syncthreads();
    }

#pragma unroll
    for (int i = 0; i < 4; ++i) {
        float4 v;
        v.x = acc[i][0]; v.y = acc[i][1]; v.z = acc[i][2]; v.w = acc[i][3];
        *(float4*)(C + (size_t)(bm + ty * 4 + i) * N + bn + tx * 4) = v;
    }
}

// branchless value-only sorted top-4 insert: 7 min/max ops
#define TOP4V_INSERT(mv)                                           \
    do {                                                           \
        float _x  = (mv);                                          \
        float _n0 = fminf(b0, _x);  float _y0 = fmaxf(b0, _x); b0 = _n0; \
        float _n1 = fminf(b1, _y0); float _y1 = fmaxf(b1, _y0); b1 = _n1; \
        float _n2 = fminf(b2, _y1); float _y2 = fmaxf(b2, _y1); b2 = _n2; \
        b3 = fminf(b3, _y2);                                       \
    } while (0)

// stable (dd, j) insert into sorted top-3 (d0<=d1<=d2v), idx tiebreak
#define TOP3JD_INSERT(dd, j)                                       \
    do {                                                           \
        bool lt2 = ((dd) < d2v) || ((dd) == d2v && (j) < j2);      \
        if (lt2) {                                                 \
            bool lt1 = ((dd) < d1) || ((dd) == d1 && (j) < j1);    \
            if (lt1) {                                             \
                d2v = d1; j2 = j1;                                 \
                bool lt0 = ((dd) < d0) || ((dd) == d0 && (j) < j0);\
                if (lt0) { d1 = d0; j1 = j0; d0 = (dd); j0 = (j); }\
                else     { d1 = (dd); j1 = (j); }                  \
            } else { d2v = (dd); j2 = (j); }                       \
        }                                                          \
    } while (0)

// named slab registers — literal indices only
#define DECLS(s) float px##s, py##s, pz##s, pw##s;
#define LOADS(s) { float4 _p = pack[base + ((s) << 6) + lane]; \
                   px##s = _p.x; py##s = _p.y; pz##s = _p.z; pw##s = _p.w; }
#define SAMPW(s) samp[wave][((s) << 6) + lane] = make_float4(px##s, py##s, pz##s, pw##s);
// phase-2 slot: 3 FMA (threshold as seed) + 1 cmp covers 64 pairs;
// survivor walk is uniform-scalar, lane 0 writes the ring
#define SLOTF(s)                                                               \
    {                                                                          \
        float acc = fmaf(qxx, px##s, fmaf(qyy, py##s, fmaf(qzz, pz##s, tq))); \
        unsigned long long mk = __ballot(acc >= pw##s);                        \
        while (mk) {                                                           \
            int l = __builtin_ctzll(mk);                                       \
            mk &= mk - 1;                                                      \
            if (is0 && cnt < CAP)                                              \
                myring[cnt] = (unsigned short)(base + ((s) << 6) + l);         \
            ++cnt;                                                             \
        }                                                                      \
    }
#define X16(M) M(0) M(1) M(2) M(3) M(4) M(5) M(6) M(7) \
               M(8) M(9) M(10) M(11) M(12) M(13) M(14) M(15)
#define X4(M)  M(0) M(1) M(2) M(3)

// Block: 512 threads = 8 waves, owns 64 fine points (queries).
// Wave w owns coarse slab [w*1024,(w+1)*1024), 16 pts/lane in named regs.
__global__ __launch_bounds__(512)
__attribute__((amdgpu_waves_per_eu(4, 4)))
void knn_gather(const float* __restrict__ xyz1,
                const float4* __restrict__ pack,
                const float4* __restrict__ G4,    // [N2*64]
                const float4* __restrict__ bias4, // [64]
                float4* __restrict__ out4,        // [N1*64]
                int N2) {
    __shared__ float4         samp[8][256];      // 32 KB: phase-1 sample stage
    __shared__ float          mdl[64][25];       // [q][w*3+k] row 100 B
    __shared__ float          mdl4[64][33];      // phase-1 top4 stage, row 132 B
    __shared__ int            mil[64][25];       // [q][w*3+k]
    __shared__ float          thr[64];
    __shared__ unsigned short ring[64][8 * CAP + 1];  // [q][w*CAP+e] row 258 B
    __shared__ unsigned short cnts[64][8];
    __shared__ float          swgt[64][3];
    __shared__ int            sidx[64][3];

    const int tid  = threadIdx.x;
    const int wave = __builtin_amdgcn_readfirstlane(tid >> 6);
    const int lane = tid & 63;
    const int fine = blockIdx.x * 64 + lane;

    const float qx = xyz1[3 * fine + 0];
    const float qy = xyz1[3 * fine + 1];
    const float qz = xyz1[3 * fine + 2];

    const int chunk = N2 >> 3;                 // 1024
    const int base  = wave * chunk;            // wave-uniform (SGPR)

    // ---- preload slab: 16 named float4 per lane; stage sample from regs ----
    X16(DECLS)
    X16(LOADS)
    X4(SAMPW)
    __syncthreads();

    // ---- Phase 1 (lane = query): batch-min(4) sloppy top-4 over 256 sample
    {
        float b0 = FLT_BIG, b1 = FLT_BIG, b2 = FLT_BIG, b3 = FLT_BIG;
        const float4* sp = samp[wave];
#pragma unroll 2
        for (int k = 0; k < 256; k += 4) {
            float4 p0 = sp[k + 0];              // uniform addr -> broadcast
            float4 p1 = sp[k + 1];
            float4 p2 = sp[k + 2];
            float4 p3 = sp[k + 3];
            float m0 = p0.w - fmaf(qx, p0.x, fmaf(qy, p0.y, qz * p0.z));
            float m1 = p1.w - fmaf(qx, p1.x, fmaf(qy, p1.y, qz * p1.z));
            float m2 = p2.w - fmaf(qx, p2.x, fmaf(qy, p2.y, qz * p2.z));
            float m3 = p3.w - fmaf(qx, p3.x, fmaf(qy, p3.y, qz * p3.z));
            float mm = fminf(fminf(m0, m1), fminf(m2, m3));  // batch-min:
            TOP4V_INSERT(mm);                   // under-maintains -> larger t (safe)
        }
        mdl4[lane][wave * 4 + 0] = b0;
        mdl4[lane][wave * 4 + 1] = b1;
        mdl4[lane][wave * 4 + 2] = b2;
        mdl4[lane][wave * 4 + 3] = b3;
    }
    __syncthreads();

    if (tid < 64) {
        float b0 = FLT_BIG, b1 = FLT_BIG, b2 = FLT_BIG, b3 = FLT_BIG;
#pragma unroll
        for (int w = 0; w < 8; ++w)
#pragma unroll
            for (int k = 0; k < 4; ++k)
                TOP4V_INSERT(mdl4[tid][w * 4 + k]);
        thr[tid] = b3 + MARGIN;   // sample-4th >= true-3rd; margin covers
    }                              // formula-rounding differences vs ref d2
    __syncthreads();

    // ---- Phase 2 (lane = point): per query broadcast, ballot-filter ----
    {
        const float qt_own = thr[lane];
        const bool  is0    = (lane == 0);
#pragma unroll 1
        for (int q = 0; q < 64; ++q) {
            float qxx = rlf(qx, q);
            float qyy = rlf(qy, q);
            float qzz = rlf(qz, q);
            float tq  = rlf(qt_own, q);
            int cnt = 0;
            unsigned short* myring = &ring[q][wave * CAP];
            X16(SLOTF)
            if (is0) cnts[q][wave] = (unsigned short)(cnt < CAP ? cnt : CAP);
        }
    }
    __syncthreads();

    // ---- Selection stage A: thread (q,w) scores ring[q][w] with the exact
    //      reference-f32 formula, keeps stable top-3 ----
    {
        const int q  = tid >> 3;
        const int w  = tid & 7;
        const int fq = blockIdx.x * 64 + q;
        const float sqx = xyz1[3 * fq + 0];
        const float sqy = xyz1[3 * fq + 1];
        const float sqz = xyz1[3 * fq + 2];
        // q_sq = (qx*qx + qy*qy) + qz*qz  (no contraction, ref rounding)
        const float qsq = __fadd_rn(__fadd_rn(__fmul_rn(sqx, sqx), __fmul_rn(sqy, sqy)),
                                    __fmul_rn(sqz, sqz));
        float d0 = FLT_BIG, d1 = FLT_BIG, d2v = FLT_BIG;
        int   j0 = 0x7fffffff, j1 = 0x7fffffff, j2 = 0x7fffffff;
        const int n = (int)cnts[q][w];
        for (int e = 0; e < n; ++e) {
            const int j = ring[q][w * CAP + e];
            float4 p = pack[j];
            // x2_sq = (x*x + y*y) + z*z
            float x2s = __fadd_rn(__fadd_rn(__fmul_rn(p.x, p.x), __fmul_rn(p.y, p.y)),
                                  __fmul_rn(p.z, p.z));
            // dot = fma(qz,z, fma(qy,y, rn(qx*x)))  — BLAS k-ascending chain
            float dot = __fmaf_rn(sqz, p.z, __fmaf_rn(sqy, p.y, __fmul_rn(sqx, p.x)));
            // d2 = (q_sq + x2_sq) - 2*dot
            float dd = __fsub_rn(__fadd_rn(qsq, x2s), __fmul_rn(2.0f, dot));
            TOP3JD_INSERT(dd, j);
        }
        mdl[q][w * 3 + 0] = d0;  mdl[q][w * 3 + 1] = d1;  mdl[q][w * 3 + 2] = d2v;
        mil[q][w * 3 + 0] = j0;  mil[q][w * 3 + 1] = j1;  mil[q][w * 3 + 2] = j2;
    }
    __syncthreads();

    // ---- Selection stage B: one thread per query merges 8x3, weights ----
    if (tid < 64) {
        float d0 = FLT_BIG, d1 = FLT_BIG, d2v = FLT_BIG;
        int   j0 = 0x7fffffff, j1 = 0x7fffffff, j2 = 0x7fffffff;
#pragma unroll
        for (int w = 0; w < 8; ++w)
#pragma unroll
            for (int k = 0; k < 3; ++k) {
                float dd = mdl[tid][w * 3 + k];
                int   j  = mil[tid][w * 3 + k];
                TOP3JD_INSERT(dd, j);
            }
        // f32 inverse-distance weights, reference op order
        float w0 = 1.0f / (__fadd_rn(sqrtf(fmaxf(d0,  1e-12f)), 1e-8f));
        float w1 = 1.0f / (__fadd_rn(sqrtf(fmaxf(d1,  1e-12f)), 1e-8f));
        float w2 = 1.0f / (__fadd_rn(sqrtf(fmaxf(d2v, 1e-12f)), 1e-8f));
        float wsum = __fadd_rn(__fadd_rn(w0, w1), w2);
        swgt[tid][0] = w0 / wsum; sidx[tid][0] = j0;
        swgt[tid][1] = w1 / wsum; sidx[tid][1] = j1;
        swgt[tid][2] = w2 / wsum; sidx[tid][2] = j2;
    }
    __syncthreads();

    // ---- Gather: out[fine] = w0*G[j0] + w1*G[j1] + w2*G[j2] + b ----
    const float4 bb = bias4[lane];
#pragma unroll
    for (int p = 0; p < 8; ++p) {
        int fl = wave * 8 + p;
        float w0 = swgt[fl][0];
        float w1 = swgt[fl][1];
        float w2 = swgt[fl][2];
        int j0 = sidx[fl][0];
        int j1 = sidx[fl][1];
        int j2 = sidx[fl][2];
        float4 g0 = G4[(size_t)j0 * 64 + lane];
        float4 g1 = G4[(size_t)j1 * 64 + lane];
        float4 g2 = G4[(size_t)j2 * 64 + lane];
        float4 o;
        o.x = fmaf(w0, g0.x, fmaf(w1, g1.x, fmaf(w2, g2.x, bb.x)));
        o.y = fmaf(w0, g0.y, fmaf(w1, g1.y, fmaf(w2, g2.y, bb.y)));
        o.z = fmaf(w0, g0.z, fmaf(w1, g1.z, fmaf(w2, g2.z, bb.z)));
        o.w = fmaf(w0, g0.w, fmaf(w1, g1.w, fmaf(w2, g2.w, bb.w)));
        out4[(size_t)(blockIdx.x * 64 + fl) * 64 + lane] = o;
    }
}

extern "C" void kernel_launch(void* const* d_in, const int* in_sizes, int n_in,
                              void* d_out, int out_size, void* d_ws, size_t ws_size,
                              hipStream_t stream) {
    const float* xyz1 = (const float*)d_in[0];
    const float* xyz2 = (const float*)d_in[1];
    // d_in[2] = feature1 (unused by the reference computation)
    const float* f2   = (const float*)d_in[3];
    const float* W    = (const float*)d_in[6];
    const float* bias = (const float*)d_in[7];

    const int N1  = in_sizes[0] / 3;   // 32768
    const int N2  = in_sizes[1] / 3;   // 8192
    const int C   = in_sizes[3] / N2;  // 256
    const int OUT = in_sizes[7];       // 256

    float*  G    = (float*)d_ws;                                   // N2*OUT f32 = 8 MB
    float4* pack = (float4*)((char*)d_ws + (size_t)N2 * OUT * 4);  // N2 float4 = 128 KB

    prep_kernel<<<(N2 + 255) / 256, 256, 0, stream>>>(xyz2, pack, N2);

    dim3 ggrid(N2 / 64, OUT / 64);
    gemm_nt_f32<<<ggrid, 256, 0, stream>>>(f2, W, G, N2, OUT, C);

    knn_gather<<<N1 / 64, 512, 0, stream>>>(xyz1, pack, (const float4*)G,
                                            (const float4*)bias, (float4*)d_out, N2);
}